// Round 8
// baseline (757.603 us; speedup 1.0000x reference)
//
#include <hip/hip_runtime.h>

#define NB 2048
#define NT 2048
#define NH 16

#define OFF_IMP   1L
#define OFF_TRAIN (1L + (long)NB * NT)
#define OFF_EVALS (OFF_TRAIN + NB)
#define OFF_EMASK (OFF_EVALS + (long)NB * NT)

// ws layout: num_t[NT] | den_t[NT] | amt[NB*NT] (path A)  or  rep[NREP*NT] (path B)
#define WS_AMT_OFF 4096
#define NREP 64

// ---------------- copies + workspace zeroing ----------------
__global__ void copy_zero_kernel(const float* __restrict__ evals,
                                 const float* __restrict__ emask,
                                 const float* __restrict__ is_train,
                                 float* __restrict__ out,
                                 float* __restrict__ ws,
                                 int n_zero) {
    long gid = (long)blockIdx.x * blockDim.x + threadIdx.x;
    if (gid < n_zero) ws[gid] = 0.0f;
    const long n1 = (long)NB * NT;
    const long total = NB + 2 * n1;
    const long stride = (long)gridDim.x * blockDim.x;
    for (long i = gid; i < total; i += stride) {
        if (i < NB)            out[OFF_TRAIN + i] = is_train[i];
        else if (i < NB + n1)  out[OFF_EVALS + (i - NB)] = evals[i - NB];
        else                   out[OFF_EMASK + (i - NB - n1)] = emask[i - NB - n1];
    }
}

// ---------------- LSTM scan: gate-parallel, 64 lanes = 1 batch ----------------
// lane = gate*16 + j  (gate order: i, f, g, o — torch LSTMCell)
__device__ __forceinline__ float rl(float v, int srcLane) {
    return __int_as_float(__builtin_amdgcn_readlane(__float_as_int(v), srcLane));
}

// One LSTM step. Arithmetic = round-2's exact association (passed, absmax
// 0.0078). Gathers = round-4's verified ds_swizzle/ds_bpermute. h broadcast =
// 16 readlanes (bit-exact) consumed by scalar v_fma with SGPR operand —
// no LDS round trip, no f2 packing movs.
#define STEP(xx, mm, XI, AI) do {                                              \
    float d0 = hs[0] * Wh[0];   d0 = fmaf(hs[1], Wh[1], d0);                   \
    d0 = fmaf(hs[2], Wh[2], d0); d0 = fmaf(hs[3], Wh[3], d0);                  \
    float d1 = hs[4] * Wh[4];   d1 = fmaf(hs[5], Wh[5], d1);                   \
    d1 = fmaf(hs[6], Wh[6], d1); d1 = fmaf(hs[7], Wh[7], d1);                  \
    float d2 = hs[8] * Wh[8];   d2 = fmaf(hs[9], Wh[9], d2);                   \
    d2 = fmaf(hs[10], Wh[10], d2); d2 = fmaf(hs[11], Wh[11], d2);              \
    float d3 = hs[12] * Wh[12]; d3 = fmaf(hs[13], Wh[13], d3);                 \
    d3 = fmaf(hs[14], Wh[14], d3); d3 = fmaf(hs[15], Wh[15], d3);              \
    const float dot = (d0 + d1) + (d2 + d3);                                   \
    float r0 = hs[0] * Wr[0];   r0 = fmaf(hs[1], Wr[1], r0);                   \
    r0 = fmaf(hs[2], Wr[2], r0); r0 = fmaf(hs[3], Wr[3], r0);                  \
    float r1 = hs[4] * Wr[4];   r1 = fmaf(hs[5], Wr[5], r1);                   \
    r1 = fmaf(hs[6], Wr[6], r1); r1 = fmaf(hs[7], Wr[7], r1);                  \
    float r2 = hs[8] * Wr[8];   r2 = fmaf(hs[9], Wr[9], r2);                   \
    r2 = fmaf(hs[10], Wr[10], r2); r2 = fmaf(hs[11], Wr[11], r2);              \
    float r3 = hs[12] * Wr[12]; r3 = fmaf(hs[13], Wr[13], r3);                 \
    r3 = fmaf(hs[14], Wr[14], r3); r3 = fmaf(hs[15], Wr[15], r3);              \
    const float xh  = brg + ((r0 + r1) + (r2 + r3));                           \
    const float dxm = (xx) - xh;                                               \
    const float xc  = fmaf((mm), dxm, xh);                                     \
    const float av  = fabsf(dxm) * (mm);                                       \
    const float gate = fmaf(wx0, xc, dot + fmaf(wx1, (mm), bias));             \
    const float ex  = __builtin_amdgcn_exp2f(gate * cExp);                     \
    const float act = fmaf(sMul, __builtin_amdgcn_rcpf(1.0f + ex), sAdd);      \
    const int   ia  = __float_as_int(act);                                     \
    const float af  = __int_as_float(__builtin_amdgcn_ds_swizzle(ia, 0x401F)); \
    const float ag  = __int_as_float(__builtin_amdgcn_ds_bpermute(a32, ia));   \
    const float ao  = __int_as_float(__builtin_amdgcn_ds_bpermute(a48, ia));   \
    c = fmaf(af, c, act * ag);                                                 \
    const float e2 = __builtin_amdgcn_exp2f(c * cT);                           \
    const float th = fmaf(2.0f, __builtin_amdgcn_rcpf(1.0f + e2), -1.0f);      \
    const float ht = ao * th;                                                  \
    _Pragma("unroll")                                                          \
    for (int k = 0; k < NH; ++k) hs[k] = rl(ht, k);                            \
    XI = xc; AI = av;                                                          \
} while (0)

#define QUAD(XV, MV, T4) do {                                                  \
    float xi0, xi1, xi2, xi3, ai0, ai1, ai2, ai3;                              \
    STEP(XV.x, MV.x, xi0, ai0); STEP(XV.y, MV.y, xi1, ai1);                    \
    STEP(XV.z, MV.z, xi2, ai2); STEP(XV.w, MV.w, xi3, ai3);                    \
    const float sx = (q == 1) ? xi1 : (q == 2) ? xi2 : (q == 3) ? xi3 : xi0;   \
    const float sa = (q == 1) ? ai1 : (q == 2) ? ai2 : (q == 3) ? ai3 : ai0;   \
    if (ATOMIC) {                                                              \
        if (lane == 0) {                                                       \
            atomicAdd(ab + (T4) + 0, ai0); atomicAdd(ab + (T4) + 1, ai1);      \
            atomicAdd(ab + (T4) + 2, ai2); atomicAdd(ab + (T4) + 3, ai3);      \
        }                                                                      \
        if (lane < 4) ib[(T4) + q] = sx;                                       \
    } else {                                                                   \
        if (lane < 8) pst[T4] = (lane < 4) ? sx : sa;                          \
    }                                                                          \
} while (0)

template <int ATOMIC>
__global__ __launch_bounds__(64, 2)
void lstm_kernel(const float* __restrict__ values,
                 const float* __restrict__ masks,
                 const float* __restrict__ W_ih,
                 const float* __restrict__ W_hh,
                 const float* __restrict__ b_ih,
                 const float* __restrict__ b_hh,
                 const float* __restrict__ W_reg,
                 const float* __restrict__ b_reg,
                 float* __restrict__ imp,   // out + OFF_IMP
                 float* __restrict__ amt) { // A: amt[NB*NT]; B: rep[NREP*NT]
    const int lane = threadIdx.x;          // 0..63
    const int G = lane >> 4;               // gate index
    const int q = lane & 3;
    const long b = blockIdx.x;             // one batch per block/wave

    float Wh[NH], Wr[NH];
#pragma unroll
    for (int k = 0; k < NH; k += 4) {
        float4 v;
        v = *(const float4*)(W_hh + lane * NH + k); Wh[k]=v.x; Wh[k+1]=v.y; Wh[k+2]=v.z; Wh[k+3]=v.w;
        v = *(const float4*)(W_reg + k);            Wr[k]=v.x; Wr[k+1]=v.y; Wr[k+2]=v.z; Wr[k+3]=v.w;
    }
    const float wx0 = W_ih[lane * 2 + 0];
    const float wx1 = W_ih[lane * 2 + 1];
    const float bias = b_ih[lane] + b_hh[lane];
    const float brg = b_reg[0];

    const float L2E = 1.4426950408889634f;
    const float cExp = (G == 2) ? -2.0f * L2E : -L2E;  // tanh for gate g, sigmoid else
    const float cT   = -2.0f * L2E;
    const float sMul = (G == 2) ? 2.0f : 1.0f;
    const float sAdd = (G == 2) ? -1.0f : 0.0f;

    // hoisted cross-lane gather addresses (xor32 / xor48) — round-4 verified
    const int a32 = (lane ^ 32) << 2;
    const int a48 = (lane ^ 48) << 2;

    float hs[NH];
#pragma unroll
    for (int k = 0; k < NH; ++k) hs[k] = 0.0f;
    float c = 0.0f;

    const float* vb = values + b * NT;
    const float* mb = masks + b * NT;
    float* ib = imp + b * NT;
    float* ab = ATOMIC ? (amt + (long)(b & (NREP - 1)) * NT) : (amt + b * NT);
    // lanes 0-3 -> imputation column q, lanes 4-7 -> loss column q
    float* pst = ((lane < 4) ? ib : ab) + q;

    // 4 static prefetch buffers, 16-step unrolled body -> no rotation movs
    float4 xA = *(const float4*)(vb + 0),  mA = *(const float4*)(mb + 0);
    float4 xB = *(const float4*)(vb + 4),  mB = *(const float4*)(mb + 4);
    float4 xC = *(const float4*)(vb + 8),  mC = *(const float4*)(mb + 8);
    float4 xD = *(const float4*)(vb + 12), mD = *(const float4*)(mb + 12);

    for (int t = 0; t < NT; t += 16) {
        QUAD(xA, mA, t + 0);
        QUAD(xB, mB, t + 4);
        {
            const int tn = (t + 16) & (NT - 1);  // wraps harmlessly on last iter
            xA = *(const float4*)(vb + tn);      mA = *(const float4*)(mb + tn);
            xB = *(const float4*)(vb + tn + 4);  mB = *(const float4*)(mb + tn + 4);
        }
        QUAD(xC, mC, t + 8);
        QUAD(xD, mD, t + 12);
        {
            const int tn = (t + 24) & (NT - 1);
            xC = *(const float4*)(vb + tn);      mC = *(const float4*)(mb + tn);
            xD = *(const float4*)(vb + tn + 4);  mD = *(const float4*)(mb + tn + 4);
        }
    }
}

// ---------------- column-sum reduce: num_t / den_t ----------------
template <int ATOMIC>
__global__ void reduce_kernel(const float* __restrict__ masks,
                              const float* __restrict__ amt,
                              float* __restrict__ num_t,
                              float* __restrict__ den_t) {
    const int t = blockIdx.x * 256 + threadIdx.x;
    const int b0 = blockIdx.y * 32;
    float sd = 0.0f;
    for (int bb = b0; bb < b0 + 32; ++bb) sd += masks[(long)bb * NT + t];
    atomicAdd(den_t + t, sd);
    if (!ATOMIC) {
        float sn = 0.0f;
        for (int bb = b0; bb < b0 + 32; ++bb) sn += amt[(long)bb * NT + t];
        atomicAdd(num_t + t, sn);
    } else if (blockIdx.y == 0) {
        float sn = 0.0f;
        for (int r = 0; r < NREP; ++r) sn += amt[(long)r * NT + t];
        num_t[t] = sn;  // single writer
    }
}

// ---------------- loss finalize ----------------
__global__ void loss_kernel(const float* __restrict__ num_t, const float* __restrict__ den_t,
                            float* __restrict__ out) {
    const int tid = threadIdx.x;
    float s = 0.0f;
    for (int t = tid; t < NT; t += 256) s += num_t[t] / (den_t[t] + 1e-5f);
#pragma unroll
    for (int off = 32; off > 0; off >>= 1) s += __shfl_down(s, off, 64);
    __shared__ float red[4];
    if ((tid & 63) == 0) red[tid >> 6] = s;
    __syncthreads();
    if (tid == 0) out[0] = (red[0] + red[1] + red[2] + red[3]) / (float)NT;
}

extern "C" void kernel_launch(void* const* d_in, const int* in_sizes, int n_in,
                              void* d_out, int out_size, void* d_ws, size_t ws_size,
                              hipStream_t stream) {
    const float* values  = (const float*)d_in[0];
    const float* masks   = (const float*)d_in[1];
    const float* evals   = (const float*)d_in[2];
    const float* emask   = (const float*)d_in[3];
    const float* istrain = (const float*)d_in[4];
    const float* W_ih    = (const float*)d_in[5];
    const float* W_hh    = (const float*)d_in[6];
    const float* b_ih    = (const float*)d_in[7];
    const float* b_hh    = (const float*)d_in[8];
    const float* W_reg   = (const float*)d_in[9];
    const float* b_reg   = (const float*)d_in[10];

    float* out = (float*)d_out;
    float* ws = (float*)d_ws;
    float* num_t = ws;
    float* den_t = ws + NT;
    float* amt = ws + WS_AMT_OFF;

    const bool pathA = ws_size >= (size_t)(WS_AMT_OFF + (long)NB * NT) * 4;

    if (pathA) {
        copy_zero_kernel<<<1024, 256, 0, stream>>>(evals, emask, istrain, out, ws, WS_AMT_OFF);
        lstm_kernel<0><<<NB, 64, 0, stream>>>(values, masks, W_ih, W_hh, b_ih, b_hh,
                                              W_reg, b_reg, out + OFF_IMP, amt);
        reduce_kernel<0><<<dim3(NT / 256, 64), 256, 0, stream>>>(masks, amt, num_t, den_t);
    } else {
        copy_zero_kernel<<<1024, 256, 0, stream>>>(evals, emask, istrain, out, ws,
                                                   WS_AMT_OFF + NREP * NT);
        lstm_kernel<1><<<NB, 64, 0, stream>>>(values, masks, W_ih, W_hh, b_ih, b_hh,
                                              W_reg, b_reg, out + OFF_IMP, amt);
        reduce_kernel<1><<<dim3(NT / 256, 64), 256, 0, stream>>>(masks, amt, num_t, den_t);
    }
    loss_kernel<<<1, 256, 0, stream>>>(num_t, den_t, out);
}

// Round 9
// 525.512 us; speedup vs baseline: 1.4416x; 1.4416x over previous
//
#include <hip/hip_runtime.h>

#define NB 2048
#define NT 2048
#define NH 16

#define OFF_IMP   1L
#define OFF_TRAIN (1L + (long)NB * NT)
#define OFF_EVALS (OFF_TRAIN + NB)
#define OFF_EMASK (OFF_EVALS + (long)NB * NT)

// ws layout: num_t[NT] | den_t[NT] | amt[NB*NT] (path A)  or  rep[NREP*NT] (path B)
#define WS_AMT_OFF 4096
#define NREP 64

typedef float f2 __attribute__((ext_vector_type(2)));

// ---------------- copies + workspace zeroing ----------------
__global__ void copy_zero_kernel(const float* __restrict__ evals,
                                 const float* __restrict__ emask,
                                 const float* __restrict__ is_train,
                                 float* __restrict__ out,
                                 float* __restrict__ ws,
                                 int n_zero) {
    long gid = (long)blockIdx.x * blockDim.x + threadIdx.x;
    if (gid < n_zero) ws[gid] = 0.0f;
    const long n1 = (long)NB * NT;
    const long total = NB + 2 * n1;
    const long stride = (long)gridDim.x * blockDim.x;
    for (long i = gid; i < total; i += stride) {
        if (i < NB)            out[OFF_TRAIN + i] = is_train[i];
        else if (i < NB + n1)  out[OFF_EVALS + (i - NB)] = evals[i - NB];
        else                   out[OFF_EMASK + (i - NB - n1)] = emask[i - NB - n1];
    }
}

// ---------------- LSTM scan: 16 lanes = 1 batch, 4 batches per wave --------
// Lane (g, j) owns unit j of batch g and computes ALL FOUR gate rows locally:
// no cross-lane gathers at all. h broadcast: 1 ds_write + 4 ds_read_b128 per
// lane within the group's private LDS row (same-wave DS order, no barrier —
// R4-verified pattern). LDS h layout is PRE-PERMUTED [h0,h4,h1,h5,...] so the
// b128 reads give f2 pairs (h_k, h_{k+4}) that reproduce R8's exact verified
// summation order: d0..d3 = chains over consecutive 4, dot=(d0+d1)+(d2+d3).

#define L2E 1.4426950408889634f

#define DOT16(W, RES) do {                                                     \
    f2 _a = H2[0] * W[0];                                                      \
    f2 _b = H2[4] * W[4];                                                      \
    _a = __builtin_elementwise_fma(H2[1], W[1], _a);                           \
    _b = __builtin_elementwise_fma(H2[5], W[5], _b);                           \
    _a = __builtin_elementwise_fma(H2[2], W[2], _a);                           \
    _b = __builtin_elementwise_fma(H2[6], W[6], _b);                           \
    _a = __builtin_elementwise_fma(H2[3], W[3], _a);                           \
    _b = __builtin_elementwise_fma(H2[7], W[7], _b);                           \
    RES = (_a.x + _a.y) + (_b.x + _b.y);                                       \
} while (0)

#define STEP(xx, mm, XI, AI) do {                                              \
    float gI, gF, gG, gO, rr;                                                  \
    DOT16(WI, gI); DOT16(WF, gF); DOT16(WG, gG); DOT16(WO, gO);                \
    DOT16(WR, rr);                                                             \
    const float xh  = brg + rr;                                                \
    const float dxm = (xx) - xh;                                               \
    const float xc  = fmaf((mm), dxm, xh);                                     \
    const float av  = fabsf(dxm) * (mm);                                       \
    const float pI = fmaf(wxi0, xc, gI + fmaf(wxi1, (mm), bi));                \
    const float pF = fmaf(wxf0, xc, gF + fmaf(wxf1, (mm), bf));                \
    const float pG = fmaf(wxg0, xc, gG + fmaf(wxg1, (mm), bg));                \
    const float pO = fmaf(wxo0, xc, gO + fmaf(wxo1, (mm), bo));                \
    const float aI = __builtin_amdgcn_rcpf(1.0f + __builtin_amdgcn_exp2f(pI * (-L2E)));  \
    const float aF = __builtin_amdgcn_rcpf(1.0f + __builtin_amdgcn_exp2f(pF * (-L2E)));  \
    const float aG = fmaf(2.0f, __builtin_amdgcn_rcpf(1.0f + __builtin_amdgcn_exp2f(pG * (-2.0f * L2E))), -1.0f); \
    const float aO = __builtin_amdgcn_rcpf(1.0f + __builtin_amdgcn_exp2f(pO * (-L2E)));  \
    c = fmaf(aF, c, aI * aG);                                                  \
    const float th = fmaf(2.0f, __builtin_amdgcn_rcpf(1.0f + __builtin_amdgcn_exp2f(c * (-2.0f * L2E))), -1.0f); \
    const float ht = aO * th;                                                  \
    hsh[hpos] = ht;                                                            \
    {                                                                          \
        const float4 h0_ = *(const float4*)(hsh + (g << 4) + 0);               \
        const float4 h1_ = *(const float4*)(hsh + (g << 4) + 4);               \
        const float4 h2_ = *(const float4*)(hsh + (g << 4) + 8);               \
        const float4 h3_ = *(const float4*)(hsh + (g << 4) + 12);              \
        H2[0] = (f2){h0_.x, h0_.y}; H2[1] = (f2){h0_.z, h0_.w};                \
        H2[2] = (f2){h1_.x, h1_.y}; H2[3] = (f2){h1_.z, h1_.w};                \
        H2[4] = (f2){h2_.x, h2_.y}; H2[5] = (f2){h2_.z, h2_.w};                \
        H2[6] = (f2){h3_.x, h3_.y}; H2[7] = (f2){h3_.z, h3_.w};                \
    }                                                                          \
    XI = xc; AI = av;                                                          \
} while (0)

#define QUAD(XV, MV, T4) do {                                                  \
    float xi0, xi1, xi2, xi3, ai0, ai1, ai2, ai3;                              \
    STEP(XV.x, MV.x, xi0, ai0); STEP(XV.y, MV.y, xi1, ai1);                    \
    STEP(XV.z, MV.z, xi2, ai2); STEP(XV.w, MV.w, xi3, ai3);                    \
    if (ATOMIC) {                                                              \
        if (j == 0) {                                                          \
            atomicAdd(ab + (T4) + 0, ai0); atomicAdd(ab + (T4) + 1, ai1);      \
            atomicAdd(ab + (T4) + 2, ai2); atomicAdd(ab + (T4) + 3, ai3);      \
        }                                                                      \
        if (j < 4) {                                                           \
            const float sx = (j == 1) ? xi1 : (j == 2) ? xi2 : (j == 3) ? xi3 : xi0; \
            ib[(T4) + j] = sx;                                                 \
        }                                                                      \
    } else {                                                                   \
        const int jq = j & 3;                                                  \
        const float sx = (jq == 1) ? xi1 : (jq == 2) ? xi2 : (jq == 3) ? xi3 : xi0; \
        const float sa = (jq == 1) ? ai1 : (jq == 2) ? ai2 : (jq == 3) ? ai3 : ai0; \
        if (j < 8) pst[T4] = (j < 4) ? sx : sa;                                \
    }                                                                          \
} while (0)

template <int ATOMIC>
__global__ __launch_bounds__(64, 1)
void lstm_kernel(const float* __restrict__ values,
                 const float* __restrict__ masks,
                 const float* __restrict__ W_ih,
                 const float* __restrict__ W_hh,
                 const float* __restrict__ b_ih,
                 const float* __restrict__ b_hh,
                 const float* __restrict__ W_reg,
                 const float* __restrict__ b_reg,
                 float* __restrict__ imp,   // out + OFF_IMP
                 float* __restrict__ amt) { // A: amt[NB*NT]; B: rep[NREP*NT]
    const int lane = threadIdx.x;          // 0..63
    const int g = lane >> 4;               // batch slot within wave
    const int j = lane & 15;               // hidden unit
    const long b = (long)blockIdx.x * 4 + g;

    // Per-lane weights: all 4 W_hh gate rows for unit j + W_reg, packed as
    // f2 pairs (w_k, w_{k+4}) matching the permuted LDS h layout.
    f2 WI[8], WF[8], WG[8], WO[8], WR[8];
    {
        const float* rI = W_hh + (0 * NH + j) * NH;
        const float* rF = W_hh + (1 * NH + j) * NH;
        const float* rG = W_hh + (2 * NH + j) * NH;
        const float* rO = W_hh + (3 * NH + j) * NH;
#pragma unroll
        for (int k = 0; k < 4; ++k) {
            WI[k] = (f2){rI[k], rI[k + 4]};  WI[4 + k] = (f2){rI[8 + k], rI[12 + k]};
            WF[k] = (f2){rF[k], rF[k + 4]};  WF[4 + k] = (f2){rF[8 + k], rF[12 + k]};
            WG[k] = (f2){rG[k], rG[k + 4]};  WG[4 + k] = (f2){rG[8 + k], rG[12 + k]};
            WO[k] = (f2){rO[k], rO[k + 4]};  WO[4 + k] = (f2){rO[8 + k], rO[12 + k]};
            WR[k] = (f2){W_reg[k], W_reg[k + 4]};
            WR[4 + k] = (f2){W_reg[8 + k], W_reg[12 + k]};
        }
    }
    const float wxi0 = W_ih[(0 * NH + j) * 2 + 0], wxi1 = W_ih[(0 * NH + j) * 2 + 1];
    const float wxf0 = W_ih[(1 * NH + j) * 2 + 0], wxf1 = W_ih[(1 * NH + j) * 2 + 1];
    const float wxg0 = W_ih[(2 * NH + j) * 2 + 0], wxg1 = W_ih[(2 * NH + j) * 2 + 1];
    const float wxo0 = W_ih[(3 * NH + j) * 2 + 0], wxo1 = W_ih[(3 * NH + j) * 2 + 1];
    const float bi = b_ih[0 * NH + j] + b_hh[0 * NH + j];
    const float bf = b_ih[1 * NH + j] + b_hh[1 * NH + j];
    const float bg = b_ih[2 * NH + j] + b_hh[2 * NH + j];
    const float bo = b_ih[3 * NH + j] + b_hh[3 * NH + j];
    const float brg = b_reg[0];

    f2 H2[8];
#pragma unroll
    for (int k = 0; k < 8; ++k) H2[k] = (f2){0.0f, 0.0f};
    float c = 0.0f;

    // Permuted h store position: layout [h0,h4,h1,h5,h2,h6,h3,h7, h8,h12,...]
    __shared__ __align__(16) float hsh[64];
    const int jj = j & 7;
    const int hpos = (g << 4) + ((j >> 3) << 3) + ((jj & 3) << 1) + (jj >> 2);

    const float* vb = values + b * NT;
    const float* mb = masks + b * NT;
    float* ib = imp + b * NT;
    float* ab = ATOMIC ? (amt + (long)(b & (NREP - 1)) * NT) : (amt + b * NT);
    // lanes j=0..3 -> imputation col jq, lanes j=4..7 -> loss col jq
    float* pst = ((j < 4) ? ib : ab) + (j & 3);

    // 4 static prefetch buffers, 16-step unrolled body
    float4 xA = *(const float4*)(vb + 0),  mA = *(const float4*)(mb + 0);
    float4 xB = *(const float4*)(vb + 4),  mB = *(const float4*)(mb + 4);
    float4 xC = *(const float4*)(vb + 8),  mC = *(const float4*)(mb + 8);
    float4 xD = *(const float4*)(vb + 12), mD = *(const float4*)(mb + 12);

    for (int t = 0; t < NT; t += 16) {
        QUAD(xA, mA, t + 0);
        QUAD(xB, mB, t + 4);
        {
            const int tn = (t + 16) & (NT - 1);  // wraps harmlessly on last iter
            xA = *(const float4*)(vb + tn);      mA = *(const float4*)(mb + tn);
            xB = *(const float4*)(vb + tn + 4);  mB = *(const float4*)(mb + tn + 4);
        }
        QUAD(xC, mC, t + 8);
        QUAD(xD, mD, t + 12);
        {
            const int tn = (t + 24) & (NT - 1);
            xC = *(const float4*)(vb + tn);      mC = *(const float4*)(mb + tn);
            xD = *(const float4*)(vb + tn + 4);  mD = *(const float4*)(mb + tn + 4);
        }
    }
}

// ---------------- column-sum reduce: num_t / den_t ----------------
template <int ATOMIC>
__global__ void reduce_kernel(const float* __restrict__ masks,
                              const float* __restrict__ amt,
                              float* __restrict__ num_t,
                              float* __restrict__ den_t) {
    const int t = blockIdx.x * 256 + threadIdx.x;
    const int b0 = blockIdx.y * 32;
    float sd = 0.0f;
    for (int bb = b0; bb < b0 + 32; ++bb) sd += masks[(long)bb * NT + t];
    atomicAdd(den_t + t, sd);
    if (!ATOMIC) {
        float sn = 0.0f;
        for (int bb = b0; bb < b0 + 32; ++bb) sn += amt[(long)bb * NT + t];
        atomicAdd(num_t + t, sn);
    } else if (blockIdx.y == 0) {
        float sn = 0.0f;
        for (int r = 0; r < NREP; ++r) sn += amt[(long)r * NT + t];
        num_t[t] = sn;  // single writer
    }
}

// ---------------- loss finalize ----------------
__global__ void loss_kernel(const float* __restrict__ num_t, const float* __restrict__ den_t,
                            float* __restrict__ out) {
    const int tid = threadIdx.x;
    float s = 0.0f;
    for (int t = tid; t < NT; t += 256) s += num_t[t] / (den_t[t] + 1e-5f);
#pragma unroll
    for (int off = 32; off > 0; off >>= 1) s += __shfl_down(s, off, 64);
    __shared__ float red[4];
    if ((tid & 63) == 0) red[tid >> 6] = s;
    __syncthreads();
    if (tid == 0) out[0] = (red[0] + red[1] + red[2] + red[3]) / (float)NT;
}

extern "C" void kernel_launch(void* const* d_in, const int* in_sizes, int n_in,
                              void* d_out, int out_size, void* d_ws, size_t ws_size,
                              hipStream_t stream) {
    const float* values  = (const float*)d_in[0];
    const float* masks   = (const float*)d_in[1];
    const float* evals   = (const float*)d_in[2];
    const float* emask   = (const float*)d_in[3];
    const float* istrain = (const float*)d_in[4];
    const float* W_ih    = (const float*)d_in[5];
    const float* W_hh    = (const float*)d_in[6];
    const float* b_ih    = (const float*)d_in[7];
    const float* b_hh    = (const float*)d_in[8];
    const float* W_reg   = (const float*)d_in[9];
    const float* b_reg   = (const float*)d_in[10];

    float* out = (float*)d_out;
    float* ws = (float*)d_ws;
    float* num_t = ws;
    float* den_t = ws + NT;
    float* amt = ws + WS_AMT_OFF;

    const bool pathA = ws_size >= (size_t)(WS_AMT_OFF + (long)NB * NT) * 4;

    if (pathA) {
        copy_zero_kernel<<<1024, 256, 0, stream>>>(evals, emask, istrain, out, ws, WS_AMT_OFF);
        lstm_kernel<0><<<NB / 4, 64, 0, stream>>>(values, masks, W_ih, W_hh, b_ih, b_hh,
                                                  W_reg, b_reg, out + OFF_IMP, amt);
        reduce_kernel<0><<<dim3(NT / 256, 64), 256, 0, stream>>>(masks, amt, num_t, den_t);
    } else {
        copy_zero_kernel<<<1024, 256, 0, stream>>>(evals, emask, istrain, out, ws,
                                                   WS_AMT_OFF + NREP * NT);
        lstm_kernel<1><<<NB / 4, 64, 0, stream>>>(values, masks, W_ih, W_hh, b_ih, b_hh,
                                                  W_reg, b_reg, out + OFF_IMP, amt);
        reduce_kernel<1><<<dim3(NT / 256, 64), 256, 0, stream>>>(masks, amt, num_t, den_t);
    }
    loss_kernel<<<1, 256, 0, stream>>>(num_t, den_t, out);
}